// Round 14
// baseline (244.550 us; speedup 1.0000x reference)
//
#include <hip/hip_runtime.h>
#include <hip/hip_cooperative_groups.h>
#include <math.h>

namespace cg = cooperative_groups;

#define W3 96
#define HW 9216        // 96*96
#define DHW 884736     // 96^3
#define NB 2
#define BIGL (1<<30)
#define INF10 1.0e10f
#define CAND_CAP 8192
#define NTHR 384
#define NJOBS 768      // NB*96*4 quarter-slice jobs
#define NCU 256

// accumulator area (4B words) at ws offset 0
#define A_ROOTCNT 0    // 2 ints
#define A_ROOTS   2    // 2*8 ints
#define A_CANDCNT 18   // 2 ints
#define A_SUMS    28   // 2*12 floats: [accA(4), accM(4), cnt(4)] per b
#define A_TOTAL   64

__constant__ int c_offs[13][3] = {
    {-1,-1,-1},{-1,-1,0},{-1,-1,1},
    {-1, 0,-1},{-1, 0,0},{-1, 0,1},
    {-1, 1,-1},{-1, 1,0},{-1, 1,1},
    { 0,-1,-1},{ 0,-1,0},{ 0,-1,1},
    { 0, 0,-1}};

struct SP1 { int l[512]; int flag; };
struct SP4 { float A[96 * 101]; int qlo, qhi; };
struct SP5 { float A[96 * 101]; float Bf[24 * 101]; float red[6][12];
             int hlo, hhi, wlo, whi; };
union SMem { SP1 p1; SP4 p4; SP5 p5; };

__device__ __forceinline__ int ufind(int* __restrict__ lb, int v) {
    int p = lb[v];
    if (p == v) return p;
    int root = p;
    while (true) { int pp = lb[root]; if (pp == root) break; root = pp; }
    if (root < p) atomicMin(&lb[v], root);   // compression: monotone, same-comp
    return root;
}

__device__ void unite(int* __restrict__ lb, int a, int b) {
    while (true) {
        a = ufind(lb, a); b = ufind(lb, b);
        if (a == b) return;
        int mn = min(a, b), mx = max(a, b);
        int old = atomicMin(&lb[mx], mn);
        if (old == mx) return;
        a = old; b = mn;
    }
}

__device__ __forceinline__ int gfind(const int* __restrict__ lb, int t) {
    while (true) { int p = lb[t]; if (p == t) break; t = p; }
    return t;
}

__device__ __forceinline__ int rankc2(int t, const int rt[8], int n) {
    int c = 1;
    #pragma unroll
    for (int p = 0; p < 8; p++) c += (p < n && rt[p] < t) ? 1 : 0;
    return c;
}

__device__ __forceinline__ int wrmin(int v) {
    v = min(v, __shfl_xor(v, 32, 64)); v = min(v, __shfl_xor(v, 16, 64));
    v = min(v, __shfl_xor(v, 8, 64));  v = min(v, __shfl_xor(v, 4, 64));
    v = min(v, __shfl_xor(v, 2, 64));  v = min(v, __shfl_xor(v, 1, 64));
    return v;
}
__device__ __forceinline__ int wrmax(int v) {
    v = max(v, __shfl_xor(v, 32, 64)); v = max(v, __shfl_xor(v, 16, 64));
    v = max(v, __shfl_xor(v, 8, 64));  v = max(v, __shfl_xor(v, 4, 64));
    v = max(v, __shfl_xor(v, 2, 64));  v = max(v, __shfl_xor(v, 1, 64));
    return v;
}
__device__ __forceinline__ float wred(float v) {
    v += __shfl_xor(v, 32, 64); v += __shfl_xor(v, 16, 64);
    v += __shfl_xor(v, 8, 64);  v += __shfl_xor(v, 4, 64);
    v += __shfl_xor(v, 2, 64);  v += __shfl_xor(v, 1, 64);
    return v;
}

// ---- Phase 1: per-tile CCL (4x4x32 tiles, barriered min-pool + jump) ----
__device__ void phase1(const int* __restrict__ y, int* __restrict__ lab,
                       int* __restrict__ acc, int* __restrict__ cand,
                       SP1* sm, int blk, int nblk, int t) {
    for (int tile = blk; tile < NB * 1728; tile += nblk) {
        int b = tile / 1728, tb = tile - b * 1728;
        int tz = tb / 72, rr2 = tb - tz * 72, ty = rr2 / 3, tx = rr2 - ty * 3;
        int d0 = tz * 4, h0 = ty * 4, w0 = tx * 32;
        const int* yb = y + b * DHW;
        int* lb = lab + b * DHW;
        if (t == 0) sm->flag = 0;
        __syncthreads();   // flag zeroed; previous tile's l[] reads done
        int e0 = t, e1 = t + NTHR;
        int has1 = (e1 < 512);
        int dz0 = e0 >> 7, dy0 = (e0 >> 5) & 3, dx0 = e0 & 31;
        int dz1 = e1 >> 7, dy1 = (e1 >> 5) & 3, dx1 = e1 & 31;
        int g0 = (d0 + dz0) * HW + (h0 + dy0) * W3 + (w0 + dx0);
        int g1 = (d0 + dz1) * HW + (h0 + dy1) * W3 + (w0 + dx1);
        int m0 = yb[g0] > 0;
        int m1 = has1 ? (yb[g1] > 0) : 0;
        sm->l[e0] = m0 ? e0 : 0x7FFF0000;
        if (has1) sm->l[e1] = m1 ? e1 : 0x7FFF0000;
        if (m0 | m1) sm->flag = 1;
        __syncthreads();
        if (sm->flag) {
            int* l = sm->l;
            for (int it = 0; it < 7; it++) {
                int n0 = 0, n1 = 0;
                if (m0) { n0 = l[e0]; if (dx0 > 0) n0 = min(n0, l[e0 - 1]);  if (dx0 < 31) n0 = min(n0, l[e0 + 1]); }
                if (m1) { n1 = l[e1]; if (dx1 > 0) n1 = min(n1, l[e1 - 1]);  if (dx1 < 31) n1 = min(n1, l[e1 + 1]); }
                __syncthreads();
                if (m0) l[e0] = n0;  if (m1) l[e1] = n1;
                __syncthreads();
                if (m0) { n0 = l[e0]; if (dy0 > 0) n0 = min(n0, l[e0 - 32]); if (dy0 < 3) n0 = min(n0, l[e0 + 32]); }
                if (m1) { n1 = l[e1]; if (dy1 > 0) n1 = min(n1, l[e1 - 32]); if (dy1 < 3) n1 = min(n1, l[e1 + 32]); }
                __syncthreads();
                if (m0) l[e0] = n0;  if (m1) l[e1] = n1;
                __syncthreads();
                if (m0) { n0 = l[e0]; if (dz0 > 0) n0 = min(n0, l[e0 - 128]); if (dz0 < 3) n0 = min(n0, l[e0 + 128]); }
                if (m1) { n1 = l[e1]; if (dz1 > 0) n1 = min(n1, l[e1 - 128]); if (dz1 < 3) n1 = min(n1, l[e1 + 128]); }
                __syncthreads();
                if (m0) l[e0] = n0;  if (m1) l[e1] = n1;
                __syncthreads();
                if (m0) n0 = l[l[e0]];
                if (m1) n1 = l[l[e1]];
                __syncthreads();
                if (m0) l[e0] = n0;  if (m1) l[e1] = n1;
                __syncthreads();
            }
            if (m0) {
                int r = sm->l[e0]; while (sm->l[r] != r) r = sm->l[r];
                lb[g0] = (d0 + (r >> 7)) * HW + (h0 + ((r >> 5) & 3)) * W3 + (w0 + (r & 31));
                if (r == e0) { int c = atomicAdd(&acc[A_CANDCNT + b], 1);
                               if (c < CAND_CAP) cand[b * CAND_CAP + c] = g0; }
            }
            if (m1) {
                int r = sm->l[e1]; while (sm->l[r] != r) r = sm->l[r];
                lb[g1] = (d0 + (r >> 7)) * HW + (h0 + ((r >> 5) & 3)) * W3 + (w0 + (r & 31));
                if (r == e1) { int c = atomicAdd(&acc[A_CANDCNT + b], 1);
                               if (c < CAND_CAP) cand[b * CAND_CAP + c] = g1; }
            }
        }
        __syncthreads();   // protect l[] reuse for next tile
    }
}

// ---- Phase 2: cross-tile boundary merge ----
__device__ void phase2(const int* __restrict__ y, int* __restrict__ lab,
                       int blk, int nblk, int t) {
    int gid = blk * NTHR + t;
    for (int i = gid; i < NB * DHW; i += nblk * NTHR) {
        int b = i / DHW, v = i - b * DHW;
        int d = v / HW; int rem = v - d * HW; int h = rem / W3; int w = rem - h * W3;
        int fz = ((d & 3) == 0), fy = ((h & 3) == 0), fx = ((w & 31) == 0);
        if (!(fz | fy | fx)) continue;
        if (y[i] <= 0) continue;
        const int* yb = y + b * DHW;
        int* lb = lab + b * DHW;
        #pragma unroll
        for (int k = 0; k < 13; k++) {
            int oz = c_offs[k][0], oy = c_offs[k][1], ox = c_offs[k][2];
            int cross = (fz && oz < 0) || (fy && oy < 0) || (fx && ox < 0);
            if (!cross) continue;
            int dd = d + oz, hh = h + oy, ww = w + ox;
            if ((unsigned)dd >= W3 || (unsigned)hh >= W3 || (unsigned)ww >= W3) continue;
            int u = dd * HW + hh * W3 + ww;
            if (yb[u] > 0) unite(lb, v, u);
        }
    }
}

// ---- Phase 3: collect global roots ----
__device__ void phase3(const int* __restrict__ lab, int* __restrict__ acc,
                       const int* __restrict__ cand, int blk, int t) {
    if (blk >= NB) return;
    int b = blk;
    int cnt = acc[A_CANDCNT + b]; if (cnt > CAND_CAP) cnt = CAND_CAP;
    const int* lb = lab + (size_t)b * DHW;
    for (int i = t; i < cnt; i += NTHR) {
        int g2 = cand[b * CAND_CAP + i];
        if (lb[g2] == g2) {
            int c = atomicAdd(&acc[A_ROOTCNT + b], 1);
            if (c < 8) acc[A_ROOTS + b * 8 + c] = g2;
        }
    }
}

// ---- Phase 4: EDT D pass + key gen (g-trick, uniform q-range) ----
__device__ void phase4(const int* __restrict__ y, const int* __restrict__ lab,
                       const int* __restrict__ acc, float* __restrict__ kB,
                       SP4* sm, int blk, int nblk, int t) {
    for (int job = blk; job < NJOBS; job += nblk) {
        int b = job / 384, r = job % 384;
        int h = r >> 2, d0 = (r & 3) * 24;
        const int* lb = lab + (size_t)b * DHW;
        const int* yb = y + (size_t)b * DHW;
        if (t == 0) { sm->qlo = 127; sm->qhi = -1; }
        int n = acc[A_ROOTCNT + b]; if (n > 8) n = 8;
        int rt[8];
        #pragma unroll
        for (int p = 0; p < 8; p++) rt[p] = acc[A_ROOTS + b * 8 + p];
        __syncthreads();
        size_t vbase = (size_t)b * DHW;
        int w2 = t % 96, tq = t / 96;
        int myLo = 127, myHi = -1;
        #pragma unroll
        for (int m = 0; m < 24; m++) {
            int dd = tq + 4 * m;
            int gi = dd * HW + h * W3 + w2;
            float val = INF10;
            if (yb[gi] > 0) {
                val = 0.125f * (float)rankc2(gfind(lb, lb[gi]), rt, n);
                myLo = min(myLo, dd); myHi = max(myHi, dd);
            }
            sm->A[dd * 101 + w2] = (float)(dd * dd) + val;
        }
        myLo = wrmin(myLo); myHi = wrmax(myHi);
        if ((t & 63) == 0) { atomicMin(&sm->qlo, myLo); atomicMax(&sm->qhi, myHi); }
        __syncthreads();
        int dbase = d0 + tq * 6;
        int lo = sm->qlo, hi = sm->qhi;
        if (hi < 0) {
            #pragma unroll
            for (int k = 0; k < 6; k++)
                kB[vbase + (size_t)(dbase + k) * HW + h * W3 + w2] = INF10;
        } else {
            float best[6], pk[6];
            #pragma unroll
            for (int k = 0; k < 6; k++) { best[k] = 3.9e37f; pk[k] = (float)(dbase + k); }
            float m2q = -2.0f * (float)lo;
            for (int q = lo; q <= hi; q++) {
                float val = sm->A[q * 101 + w2];
                #pragma unroll
                for (int k = 0; k < 6; k++)
                    best[k] = fminf(best[k], fmaf(pk[k], m2q, val));
                m2q -= 2.0f;
            }
            #pragma unroll
            for (int k = 0; k < 6; k++)
                kB[vbase + (size_t)(dbase + k) * HW + h * W3 + w2] = best[k] + pk[k] * pk[k];
        }
        __syncthreads();   // protect sm reuse across jobs
    }
}

// ---- Phase 5: EDT H+W + dice accumulation (lab-free key decode) ----
__device__ void phase5(const float* __restrict__ kB, const float* __restrict__ x,
                       int* __restrict__ acc, SP5* sm, int blk, int nblk, int t) {
    for (int job = blk; job < NJOBS; job += nblk) {
        int b = job / 384, r = job % 384;
        int d = r >> 2, h0 = (r & 3) * 24;
        size_t sbase = (size_t)b * DHW + (size_t)d * HW;
        if (t == 0) { sm->hlo = 127; sm->hhi = -1; sm->wlo = 127; sm->whi = -1; }
        __syncthreads();
        int w2 = t % 96, tq = t / 96;
        int myLo = 127, myHi = -1, myWLo = 127, myWHi = -1;
        #pragma unroll
        for (int m = 0; m < 24; m++) {
            int hh = tq + 4 * m;
            float val = kB[sbase + hh * W3 + w2];
            if (val < 1.0e9f) {
                myLo = min(myLo, hh); myHi = max(myHi, hh);
                myWLo = w2; myWHi = w2;
            }
            sm->A[hh * 101 + w2] = (float)(hh * hh) + val;
        }
        if (myWHi < 0) myWLo = 127;
        myLo = wrmin(myLo); myHi = wrmax(myHi);
        myWLo = wrmin(myWLo); myWHi = wrmax(myWHi);
        if ((t & 63) == 0) {
            atomicMin(&sm->hlo, myLo); atomicMax(&sm->hhi, myHi);
            atomicMin(&sm->wlo, myWLo); atomicMax(&sm->whi, myWHi);
        }
        __syncthreads();
        // H pass
        {
            int w = t % 96, hg = t / 96;
            int hb = h0 + hg * 6;
            int lo = sm->hlo, hi = sm->hhi;
            float fw2 = (float)(w * w);
            if (hi < 0) {
                #pragma unroll
                for (int k = 0; k < 6; k++) sm->Bf[(hg * 6 + k) * 101 + w] = INF10;
            } else {
                float best[6], pk[6];
                #pragma unroll
                for (int k = 0; k < 6; k++) { best[k] = 3.9e37f; pk[k] = (float)(hb + k); }
                float m2q = -2.0f * (float)lo;
                for (int q = lo; q <= hi; q++) {
                    float val = sm->A[q * 101 + w];
                    #pragma unroll
                    for (int k = 0; k < 6; k++)
                        best[k] = fminf(best[k], fmaf(pk[k], m2q, val));
                    m2q -= 2.0f;
                }
                #pragma unroll
                for (int k = 0; k < 6; k++)
                    sm->Bf[(hg * 6 + k) * 101 + w] = best[k] + pk[k] * pk[k] + fw2;
            }
        }
        __syncthreads();
        // W pass -> final keys into A rows 0..23
        {
            int rr = t % 24, cg2 = t / 24;
            int wb = cg2 * 6;
            int lo = sm->wlo, hi = sm->whi;
            if (hi < 0) {
                #pragma unroll
                for (int k = 0; k < 6; k++) sm->A[rr * 101 + wb + k] = INF10;
            } else {
                float best[6], pk[6];
                #pragma unroll
                for (int k = 0; k < 6; k++) { best[k] = 3.9e37f; pk[k] = (float)(wb + k); }
                float m2q = -2.0f * (float)lo;
                for (int q = lo; q <= hi; q++) {
                    float val = sm->Bf[rr * 101 + q];
                    #pragma unroll
                    for (int k = 0; k < 6; k++)
                        best[k] = fminf(best[k], fmaf(pk[k], m2q, val));
                    m2q -= 2.0f;
                }
                #pragma unroll
                for (int k = 0; k < 6; k++) sm->A[rr * 101 + wb + k] = best[k] + pk[k] * pk[k];
            }
        }
        __syncthreads();
        // accumulation (coalesced, key-only)
        float aA[4] = {0,0,0,0}, aM[4] = {0,0,0,0}, aC[4] = {0,0,0,0};
        size_t qbase = sbase + (size_t)h0 * W3;
        #pragma unroll
        for (int m = 0; m < 6; m++) {
            int e = t + NTHR * m;
            int rr = e / 96, wv2 = e - rr * 96;
            float key = sm->A[rr * 101 + wv2];
            int key8 = (int)(key * 8.0f);
            int seg = (key8 & 7) - 1;
            seg = (seg < 0) ? 0 : ((seg > 3) ? 3 : seg);
            int c = (key8 < 8) ? (seg + 1) : 0;
            float xs = 1.0f / (1.0f + __expf(-x[qbase + e]));
            #pragma unroll
            for (int s = 0; s < 4; s++) {
                aA[s] += (seg == s) ? xs : 0.0f;
                aM[s] += (c == s + 1) ? xs : 0.0f;
                aC[s] += (c == s + 1) ? 1.0f : 0.0f;
            }
        }
        #pragma unroll
        for (int s = 0; s < 4; s++) { aA[s] = wred(aA[s]); aM[s] = wred(aM[s]); aC[s] = wred(aC[s]); }
        int lane = t & 63, wv = t >> 6;
        if (lane == 0) {
            #pragma unroll
            for (int s = 0; s < 4; s++) {
                sm->red[wv][s] = aA[s]; sm->red[wv][4 + s] = aM[s]; sm->red[wv][8 + s] = aC[s];
            }
        }
        __syncthreads();
        if (t < 12) {
            float v = sm->red[0][t] + sm->red[1][t] + sm->red[2][t] +
                      sm->red[3][t] + sm->red[4][t] + sm->red[5][t];
            atomicAdd((float*)&acc[A_SUMS + b * 12 + t], v);
        }
        __syncthreads();   // protect sm reuse across jobs
    }
}

__device__ void lossf(const int* __restrict__ acc, float* __restrict__ out) {
    const float* sums = (const float*)&acc[A_SUMS];
    float total = 0.0f;
    for (int b = 0; b < NB; b++) {
        int n = acc[A_ROOTCNT + b];
        int K = (n > 5) ? 5 : n;
        float s = 0.0f;
        for (int r = 0; r < 4; r++) {
            if (r < K) {
                float A = sums[b * 12 + r];
                float M = sums[b * 12 + 4 + r];
                float C = sums[b * 12 + 8 + r];
                float inter = (float)(r + 1) * M;
                float sy = (float)(r + 1) * C;
                s += 2.0f * inter / (A + sy);
            }
        }
        float Kf = (float)(K > 0 ? K : 1);
        total += (K == 0) ? 1.0f : (1.0f - s / Kf);
    }
    out[0] = total / (float)NB;
}

// ---------------- cooperative mega-kernel ----------------
__global__ __launch_bounds__(NTHR) void k_mega(const float* __restrict__ x,
                                               const int* __restrict__ y,
                                               int* acc, int* cand, int* lab,
                                               float* kB, float* out) {
    cg::grid_group gg = cg::this_grid();
    __shared__ SMem sm;
    int t = threadIdx.x, blk = blockIdx.x, nblk = gridDim.x;
    if (blk == 0 && t < A_TOTAL) acc[t] = 0;
    gg.sync();
    phase1(y, lab, acc, cand, &sm.p1, blk, nblk, t);
    gg.sync();
    phase2(y, lab, blk, nblk, t);
    gg.sync();
    phase3(lab, acc, cand, blk, t);
    gg.sync();
    phase4(y, lab, acc, kB, &sm.p4, blk, nblk, t);
    gg.sync();
    phase5(kB, x, acc, &sm.p5, blk, nblk, t);
    gg.sync();
    if (blk == 0 && t == 0) lossf(acc, out);
}

// ---------------- fallback standalone kernels (same device code) ----------------
__global__ void k_f0(int* acc) {
    if (blockIdx.x == 0 && threadIdx.x < A_TOTAL) acc[threadIdx.x] = 0;
}
__global__ __launch_bounds__(NTHR) void k_f1(const int* y, int* lab, int* acc, int* cand) {
    __shared__ SP1 sm;
    phase1(y, lab, acc, cand, &sm, blockIdx.x, gridDim.x, threadIdx.x);
}
__global__ __launch_bounds__(NTHR) void k_f2(const int* y, int* lab) {
    phase2(y, lab, blockIdx.x, gridDim.x, threadIdx.x);
}
__global__ __launch_bounds__(NTHR) void k_f3(const int* lab, int* acc, const int* cand) {
    phase3(lab, acc, cand, blockIdx.x, threadIdx.x);
}
__global__ __launch_bounds__(NTHR) void k_f4(const int* y, const int* lab,
                                             const int* acc, float* kB) {
    __shared__ SP4 sm;
    phase4(y, lab, acc, kB, &sm, blockIdx.x, gridDim.x, threadIdx.x);
}
__global__ __launch_bounds__(NTHR) void k_f5(const float* kB, const float* x, int* acc) {
    __shared__ SP5 sm;
    phase5(kB, x, acc, &sm, blockIdx.x, gridDim.x, threadIdx.x);
}
__global__ void k_f6(const int* acc, float* out) {
    if (threadIdx.x == 0 && blockIdx.x == 0) lossf(acc, out);
}

extern "C" void kernel_launch(void* const* d_in, const int* in_sizes, int n_in,
                              void* d_out, int out_size, void* d_ws, size_t ws_size,
                              hipStream_t stream) {
    const float* x = (const float*)d_in[0];
    const int*   y = (const int*)d_in[1];
    float* out = (float*)d_out;

    char* ws = (char*)d_ws;
    int*   acc  = (int*)ws;
    int*   cand = (int*)(ws + 1024);
    int*   lab  = (int*)(ws + 1024 + CAND_CAP * NB * 4);
    float* kB   = (float*)((char*)lab + (size_t)NB * DHW * 4);

    // cooperative path: grid sized by the runtime's own co-residency calc
    int maxPerCU = 0;
    hipError_t oe = hipOccupancyMaxActiveBlocksPerMultiprocessor(&maxPerCU, k_mega, NTHR, 0);
    bool done = false;
    if (oe == hipSuccess && maxPerCU > 0) {
        int nblk = maxPerCU * NCU;
        if (nblk > NJOBS) nblk = NJOBS;
        if (nblk >= NB) {
            void* args[] = {(void*)&x, (void*)&y, (void*)&acc, (void*)&cand,
                            (void*)&lab, (void*)&kB, (void*)&out};
            if (hipLaunchCooperativeKernel((void*)k_mega, dim3(nblk), dim3(NTHR),
                                           args, 0, stream) == hipSuccess)
                done = true;
        }
    }
    if (!done) {
        // fallback: identical phases as 7 kernels
        k_f0<<<1, 64, 0, stream>>>(acc);
        k_f1<<<NB * 1728, NTHR, 0, stream>>>(y, lab, acc, cand);
        k_f2<<<(NB * DHW) / NTHR, NTHR, 0, stream>>>(y, lab);
        k_f3<<<NB, NTHR, 0, stream>>>(lab, acc, cand);
        k_f4<<<NJOBS, NTHR, 0, stream>>>(y, lab, acc, kB);
        k_f5<<<NJOBS, NTHR, 0, stream>>>(kB, x, acc);
        k_f6<<<1, 64, 0, stream>>>(acc, out);
    }
}